// Round 8
// baseline (1058.601 us; speedup 1.0000x reference)
//
#include <hip/hip_runtime.h>
#include <math.h>

// RNN: T=4096 sequential steps, B=2048, N_HID=32, N_IN=1.
// Round 8: k-split @ 2 waves/SIMD, VERIFIED PRIMITIVES ONLY (no inline asm;
// r6/r7 failed on the VALU-write->DPP-read hazard inside opaque asm).
//
// One batch per wave -> 2048 waves = 2/SIMD (fills dependency stalls).
// Lane decomposition: p=lane&15, row=bit4, kh=bit5.
//   - lane carries OUTPUT o=(kh<<4)|p and accumulates k-half [16*row,16*row+16)
//   - state hk[l] = h_{16*row+p}: 16 MACs via builtin mov_dpp(row_ror)+fma
//     (compiler inserts DPP hazard nops; r4-proven pattern)
//   - partial merge: pair (p,row0,kh)+(p,row1,kh) -> ds_swizzle 0x401F
//     (xor-16, r4-verified) + commutative add (both copies bit-identical)
//   - h_o = relu(dot); relayout to hk for next step: quadrants with
//     row!=kh take the xor-32 partner (derivation: (p,1,0)<->(p,1,1) and
//     (p,0,1)<->(p,0,0) both hold/need across lane^32), via
//     __shfl_xor(.,32) (r5-verified) + cndmask.
//   - decode in o-layout: d=h_o*W_dec[o], row_shr 1/2/4/8 DPP reduce
//     (r3-verified, sum at p=15), + shfl_xor(32) partner (D_kh0+D_kh1),
//     sigmoid, store from lane 15. Off the recurrence critical path.
// Zero LDS allocation. x prefetched 8-deep (r5 scheme).

constexpr int T_STEPS = 4096;
constexpr int BATCH   = 2048;
constexpr int NH      = 32;

template <int CTRL>
__device__ __forceinline__ float dpp_f(float v) {
    return __builtin_bit_cast(float, __builtin_amdgcn_update_dpp(
        0, __builtin_bit_cast(int, v), CTRL, 0xf, 0xf, true));
}

__global__ __launch_bounds__(64) void rnn_fused_kernel(
    const float* __restrict__ x,      // [T, B]
    const float* __restrict__ hidden, // [B, NH]
    const float* __restrict__ W_ih,   // [NH]
    const float* __restrict__ W_hh,   // [NH, NH]
    const float* __restrict__ b_ih,   // [NH]
    const float* __restrict__ b_hh,   // [NH]
    const float* __restrict__ W_dec,  // [NH]
    const float* __restrict__ b_dec,  // [1]
    float* __restrict__ out)          // [T*B] decoded ++ [B*NH] h_final
{
    const int lane = threadIdx.x;       // 0..63
    const int p    = lane & 15;
    const int row  = (lane >> 4) & 1;   // k-half this lane accumulates
    const int kh   = lane >> 5;         // high bit of the output index
    const int o    = (kh << 4) | p;     // output index this lane carries
    const int b    = blockIdx.x;        // one batch element per wave

    // xp folded into the row==0 partial only (r5-verified zero-weight trick)
    const float wih0 = row ? 0.0f : W_ih[o];
    const float cb0  = row ? 0.0f : (b_ih[o] + b_hh[o]);
    const float wdO  = W_dec[o];
    const float bdec = b_dec[0];

    // ---- probe DPP row_ror:1 direction (r4-verified technique)
    int rot1 = __builtin_amdgcn_update_dpp(0, p, 0x121, 0xf, 0xf, true);
    const bool minus = (rot1 == ((p - 1) & 15));

    // ---- weights for my (output o, k-half row): wK[r] pairs with ror_r(hk)
    float wK[16];
    #pragma unroll
    for (int r = 0; r < 16; ++r) {
        int q = minus ? ((p - r) & 15) : ((p + r) & 15);
        wK[r] = W_hh[o * NH + (row << 4) + q];
    }

    // state in k-layout: hk = h_{16*row + p}
    float hk = hidden[b * NH + (row << 4) + p];
    const bool keep = (row == kh);      // relayout predicate (see header)

    // x prefetch ring, 8 deep (r5-verified block scheme)
    const float* xb = x + b;
    float xr[8];
    #pragma unroll
    for (int j = 0; j < 8; ++j) xr[j] = xb[(size_t)j * BATCH];

    float* outd = out + b;
    constexpr float NLOG2E = -1.44269504088896340736f;

    for (int t0 = 0; t0 < T_STEPS; t0 += 8) {
        const int tn = (t0 + 8 <= T_STEPS - 8) ? (t0 + 8) : (T_STEPS - 8);
        const float* xnb = xb + (size_t)tn * BATCH;
        float xn[8];
        #pragma unroll
        for (int j = 0; j < 8; ++j) xn[j] = xnb[(size_t)j * BATCH];

        #pragma unroll
        for (int j = 0; j < 8; ++j) {
            // ---- 16 MACs over my k-half, builtin DPP rotations, 2 chains
            float a0 = fmaf(xr[j], wih0, cb0);
            a0 = fmaf(hk, wK[0], a0);
            float a1 = 0.0f;
            a1 = fmaf(dpp_f<0x121>(hk), wK[ 1], a1);
            a0 = fmaf(dpp_f<0x122>(hk), wK[ 2], a0);
            a1 = fmaf(dpp_f<0x123>(hk), wK[ 3], a1);
            a0 = fmaf(dpp_f<0x124>(hk), wK[ 4], a0);
            a1 = fmaf(dpp_f<0x125>(hk), wK[ 5], a1);
            a0 = fmaf(dpp_f<0x126>(hk), wK[ 6], a0);
            a1 = fmaf(dpp_f<0x127>(hk), wK[ 7], a1);
            a0 = fmaf(dpp_f<0x128>(hk), wK[ 8], a0);
            a1 = fmaf(dpp_f<0x129>(hk), wK[ 9], a1);
            a0 = fmaf(dpp_f<0x12A>(hk), wK[10], a0);
            a1 = fmaf(dpp_f<0x12B>(hk), wK[11], a1);
            a0 = fmaf(dpp_f<0x12C>(hk), wK[12], a0);
            a1 = fmaf(dpp_f<0x12D>(hk), wK[13], a1);
            a0 = fmaf(dpp_f<0x12E>(hk), wK[14], a0);
            a1 = fmaf(dpp_f<0x12F>(hk), wK[15], a1);
            float P = a0 + a1;

            // ---- merge the two k-halves (pair differs in row-bit: xor-16)
            float Pp = __builtin_bit_cast(float, __builtin_amdgcn_ds_swizzle(
                __builtin_bit_cast(int, P), 0x401F));
            float dot = P + Pp;            // commutative: copies bit-identical
            float hO  = fmaxf(dot, 0.0f);  // h_{o} at every lane

            // ---- relayout o->k for the next step (xor-32 partner where
            //      row!=kh; see header derivation)
            float hx = __shfl_xor(hO, 32, 64);
            hk = keep ? hO : hx;

            // ---- fused decode (off critical path), o-layout
            float d = hO * wdO;
            d = d + dpp_f<0x111>(d);   // row_shr:1
            d = d + dpp_f<0x112>(d);   // row_shr:2
            d = d + dpp_f<0x114>(d);   // row_shr:4
            d = d + dpp_f<0x118>(d);   // row_shr:8 -> p==15 holds D_kh
            float dx = __shfl_xor(d, 32, 64);     // partner kh's D
            float z  = (d + dx) + bdec;
            float e  = __builtin_amdgcn_exp2f(z * NLOG2E);
            float sg = __builtin_amdgcn_rcpf(1.0f + e);
            if (lane == 15) outd[(size_t)(t0 + j) * BATCH] = sg;

            xr[j] = xn[j];
        }
    }

    // ---- final hidden state [B, NH]: hk-layout, lanes 0..31 cover all 32
    if (lane < 32)
        out[(size_t)T_STEPS * BATCH + (size_t)b * NH + (lane & 31)] = hk;
}

extern "C" void kernel_launch(void* const* d_in, const int* in_sizes, int n_in,
                              void* d_out, int out_size, void* d_ws, size_t ws_size,
                              hipStream_t stream) {
    const float* x      = (const float*)d_in[0];
    const float* hidden = (const float*)d_in[1];
    const float* W_ih   = (const float*)d_in[2];
    const float* W_hh   = (const float*)d_in[3];
    const float* b_ih   = (const float*)d_in[4];
    const float* b_hh   = (const float*)d_in[5];
    const float* W_dec  = (const float*)d_in[6];
    const float* b_dec  = (const float*)d_in[7];
    float* out          = (float*)d_out;

    dim3 grid(BATCH);   // 2048 waves = 2 per SIMD machine-wide
    dim3 block(64);
    hipLaunchKernelGGL(rnn_fused_kernel, grid, block, 0, stream,
                       x, hidden, W_ih, W_hh, b_ih, b_hh, W_dec, b_dec, out);
}

// Round 9
// 887.851 us; speedup vs baseline: 1.1923x; 1.1923x over previous
//
#include <hip/hip_runtime.h>
#include <math.h>

// RNN: T=4096 sequential steps, B=2048, N_HID=32, N_IN=1.
// Round 9 = round 8 (PASSED) + two surgical changes:
//  1. MAC chain: 16x fused asm v_fmac_f32_dpp (vs 32 builtin mov+fma).
//     r6/r7's failure is attributed to the documented CDNA hazard
//     "VALU write -> DPP read needs 2 wait states" which the compiler
//     cannot mitigate inside opaque asm. Fix: the FIRST asm block embeds
//     "s_nop 1" ahead of its fmac (single indivisible block, so the 2
//     wait states after the cndmask that wrote hk are guaranteed).
//     Accumulator operands are non-DPP reads (no hazard).
//  2. The two chain DS ops (ds_swizzle xor16 merge, shfl_xor(32)
//     relayout) -> VALU v_permlane16_swap / v_permlane32_swap
//     (builtins: compiler handles their hazards; polarity PROBED at
//     init; __has_builtin fallback to the r4-verified ds_swizzle).
// Decode stays on builtin DPP (compiler-safe, off critical path).
// Layout (r8, verified): p=lane&15, row=bit4 (k-half), kh=bit5 (out-half),
// lane carries output o=(kh<<4)|p, accumulates k-half row. 1 batch/wave,
// 2048 waves = 2/SIMD. Zero LDS. Zero DS ops in the recurrence chain.

typedef int i32x2 __attribute__((ext_vector_type(2)));

constexpr int T_STEPS = 4096;
constexpr int BATCH   = 2048;
constexpr int NH      = 32;

template <int CTRL>
__device__ __forceinline__ float dpp_f(float v) {
    return __builtin_bit_cast(float, __builtin_amdgcn_update_dpp(
        0, __builtin_bit_cast(int, v), CTRL, 0xf, 0xf, true));
}

// acc += row_ror_R(src) * wgt -- single VOP2-DPP instruction.
#define FMAC_ROR(ACC, SRC, WGT, RSTR)                                        \
    asm volatile("v_fmac_f32_dpp %0, %1, %2 " RSTR                           \
        " row_mask:0xf bank_mask:0xf bound_ctrl:0"                           \
        : "+v"(ACC) : "v"(SRC), "v"(WGT))

// First DPP read of SRC after a VALU write: embed the 2 wait states.
#define FMAC_ROR_FIRST(ACC, SRC, WGT, RSTR)                                  \
    asm volatile("s_nop 1\n\tv_fmac_f32_dpp %0, %1, %2 " RSTR                \
        " row_mask:0xf bank_mask:0xf bound_ctrl:0"                           \
        : "+v"(ACC) : "v"(SRC), "v"(WGT))

#if __has_builtin(__builtin_amdgcn_permlane16_swap)
#define HAVE_PL16 1
#else
#define HAVE_PL16 0
#endif

__global__ __launch_bounds__(64) void rnn_fused_kernel(
    const float* __restrict__ x,      // [T, B]
    const float* __restrict__ hidden, // [B, NH]
    const float* __restrict__ W_ih,   // [NH]
    const float* __restrict__ W_hh,   // [NH, NH]
    const float* __restrict__ b_ih,   // [NH]
    const float* __restrict__ b_hh,   // [NH]
    const float* __restrict__ W_dec,  // [NH]
    const float* __restrict__ b_dec,  // [1]
    float* __restrict__ out)          // [T*B] decoded ++ [B*NH] h_final
{
    const int lane = threadIdx.x;       // 0..63
    const int p    = lane & 15;
    const int row  = (lane >> 4) & 1;   // k-half this lane accumulates
    const int kh   = lane >> 5;         // high bit of the output index
    const int o    = (kh << 4) | p;     // output index this lane carries
    const int b    = blockIdx.x;        // one batch element per wave

    const float wih0 = row ? 0.0f : W_ih[o];
    const float cb0  = row ? 0.0f : (b_ih[o] + b_hh[o]);
    const float wdO  = W_dec[o];
    const float bdec = b_dec[0];

    // ---- probe DPP row_ror:1 direction (r4-verified technique)
    int rot1 = __builtin_amdgcn_update_dpp(0, p, 0x121, 0xf, 0xf, true);
    const bool minus = (rot1 == ((p - 1) & 15));

    // ---- probe permlane swap polarity (per-lane: which ret holds partner)
#if HAVE_PL16
    i32x2 pr16 = __builtin_amdgcn_permlane16_swap(lane, lane, false, false);
    const bool sel16 = (pr16[1] == (lane ^ 16));
#endif
    i32x2 pr32 = __builtin_amdgcn_permlane32_swap(lane, lane, false, false);
    const bool sel32 = (pr32[1] == (lane ^ 32));

    // ---- weights for my (output o, k-half row): wK[r] pairs with ror_r(hk)
    float wK[16];
    #pragma unroll
    for (int r = 0; r < 16; ++r) {
        int q = minus ? ((p - r) & 15) : ((p + r) & 15);
        wK[r] = W_hh[o * NH + (row << 4) + q];
    }

    // state in k-layout: hk = h_{16*row + p}
    float hk = hidden[b * NH + (row << 4) + p];
    const bool keep = (row == kh);

    // x prefetch ring, 8 deep (r5/r8-verified block scheme)
    const float* xb = x + b;
    float xr[8];
    #pragma unroll
    for (int j = 0; j < 8; ++j) xr[j] = xb[(size_t)j * BATCH];

    float* outd = out + b;
    constexpr float NLOG2E = -1.44269504088896340736f;

    for (int t0 = 0; t0 < T_STEPS; t0 += 8) {
        const int tn = (t0 + 8 <= T_STEPS - 8) ? (t0 + 8) : (T_STEPS - 8);
        const float* xnb = xb + (size_t)tn * BATCH;
        float xn[8];
        #pragma unroll
        for (int j = 0; j < 8; ++j) xn[j] = xnb[(size_t)j * BATCH];

        #pragma unroll
        for (int j = 0; j < 8; ++j) {
            // ---- 16 MACs over my k-half: fused DPP fmac, 2 chains.
            //      First asm block embeds s_nop 1 (hazard: cndmask wrote hk).
            float a0 = fmaf(xr[j], wih0, cb0);
            float a1 = 0.0f;
            FMAC_ROR_FIRST(a1, hk, wK[ 1], "row_ror:1");
            FMAC_ROR(a0, hk, wK[ 2], "row_ror:2");
            FMAC_ROR(a1, hk, wK[ 3], "row_ror:3");
            FMAC_ROR(a0, hk, wK[ 4], "row_ror:4");
            FMAC_ROR(a1, hk, wK[ 5], "row_ror:5");
            FMAC_ROR(a0, hk, wK[ 6], "row_ror:6");
            FMAC_ROR(a1, hk, wK[ 7], "row_ror:7");
            FMAC_ROR(a0, hk, wK[ 8], "row_ror:8");
            FMAC_ROR(a1, hk, wK[ 9], "row_ror:9");
            FMAC_ROR(a0, hk, wK[10], "row_ror:10");
            FMAC_ROR(a1, hk, wK[11], "row_ror:11");
            FMAC_ROR(a0, hk, wK[12], "row_ror:12");
            FMAC_ROR(a1, hk, wK[13], "row_ror:13");
            FMAC_ROR(a0, hk, wK[14], "row_ror:14");
            FMAC_ROR(a1, hk, wK[15], "row_ror:15");
            a0 = fmaf(hk, wK[0], a0);          // r=0 term (non-DPP read)
            float P = a0 + a1;

            // ---- merge the two k-halves (partner = lane^16), VALU swap
#if HAVE_PL16
            int Pb = __builtin_bit_cast(int, P);
            i32x2 s16 = __builtin_amdgcn_permlane16_swap(Pb, Pb, false, false);
            float Pp = __builtin_bit_cast(float, sel16 ? s16[1] : s16[0]);
#else
            float Pp = __builtin_bit_cast(float, __builtin_amdgcn_ds_swizzle(
                __builtin_bit_cast(int, P), 0x401F));
#endif
            float dot = P + Pp;                // commutative, copies identical
            float hO  = fmaxf(dot, 0.0f);

            // ---- relayout o->k (partner = lane^32 where row!=kh), VALU swap
            int hb = __builtin_bit_cast(int, hO);
            i32x2 s32 = __builtin_amdgcn_permlane32_swap(hb, hb, false, false);
            float hx = __builtin_bit_cast(float, sel32 ? s32[1] : s32[0]);
            hk = keep ? hO : hx;

            // ---- fused decode (builtin DPP, off critical path)
            float d = hO * wdO;
            d = d + dpp_f<0x111>(d);   // row_shr:1
            d = d + dpp_f<0x112>(d);   // row_shr:2
            d = d + dpp_f<0x114>(d);   // row_shr:4
            d = d + dpp_f<0x118>(d);   // row_shr:8 -> p==15 holds D_kh
            int db = __builtin_bit_cast(int, d);
            i32x2 ds32 = __builtin_amdgcn_permlane32_swap(db, db, false, false);
            float dx = __builtin_bit_cast(float, sel32 ? ds32[1] : ds32[0]);
            float z  = (d + dx) + bdec;
            float e  = __builtin_amdgcn_exp2f(z * NLOG2E);
            float sg = __builtin_amdgcn_rcpf(1.0f + e);
            if (lane == 15) outd[(size_t)(t0 + j) * BATCH] = sg;

            xr[j] = xn[j];
        }
    }

    // ---- final hidden state [B, NH]: hk-layout, lanes 0..31 cover all 32
    if (lane < 32)
        out[(size_t)T_STEPS * BATCH + (size_t)b * NH + (lane & 31)] = hk;
}

extern "C" void kernel_launch(void* const* d_in, const int* in_sizes, int n_in,
                              void* d_out, int out_size, void* d_ws, size_t ws_size,
                              hipStream_t stream) {
    const float* x      = (const float*)d_in[0];
    const float* hidden = (const float*)d_in[1];
    const float* W_ih   = (const float*)d_in[2];
    const float* W_hh   = (const float*)d_in[3];
    const float* b_ih   = (const float*)d_in[4];
    const float* b_hh   = (const float*)d_in[5];
    const float* W_dec  = (const float*)d_in[6];
    const float* b_dec  = (const float*)d_in[7];
    float* out          = (float*)d_out;

    dim3 grid(BATCH);   // 2048 waves = 2 per SIMD machine-wide
    dim3 block(64);
    hipLaunchKernelGGL(rnn_fused_kernel, grid, block, 0, stream,
                       x, hidden, W_ih, W_hh, b_ih, b_hh, W_dec, b_dec, out);
}